// Round 8
// baseline (3834.119 us; speedup 1.0000x reference)
//
#include <hip/hip_runtime.h>

#define NPTS 4096
#define NPT  1024
#define BATCH 16

// ---------------------------------------------------------------------------
// DPP helpers: VALU-speed cross-lane max-reduce on a packed u64 key
// (float_bits(dist)<<32)|~idx. dist>=0 -> float bits monotone; ~idx breaks
// ties toward the smaller index (== jnp.argmax first-max). Identity 0 loses
// to every real key (lo = ~p != 0 for p <= 4095).
// ---------------------------------------------------------------------------
template <int CTRL>
__device__ __forceinline__ void dpp_keymax(unsigned long long& key)
{
    const int klo = (int)(unsigned int)key;
    const int khi = (int)(unsigned int)(key >> 32);
    const int nlo = __builtin_amdgcn_update_dpp(0, klo, CTRL, 0xF, 0xF, false);
    const int nhi = __builtin_amdgcn_update_dpp(0, khi, CTRL, 0xF, 0xF, false);
    const unsigned long long ok =
        ((unsigned long long)(unsigned int)nhi << 32) | (unsigned int)nlo;
    key = (ok > key) ? ok : key;
}

template <int CTRL>
__device__ __forceinline__ void dpp_keymax_xyz(unsigned long long& key,
                                               float& x, float& y, float& z)
{
    const int klo = (int)(unsigned int)key;
    const int khi = (int)(unsigned int)(key >> 32);
    const int nlo = __builtin_amdgcn_update_dpp(0, klo, CTRL, 0xF, 0xF, false);
    const int nhi = __builtin_amdgcn_update_dpp(0, khi, CTRL, 0xF, 0xF, false);
    const int nx  = __builtin_amdgcn_update_dpp(0, __float_as_int(x), CTRL, 0xF, 0xF, false);
    const int ny  = __builtin_amdgcn_update_dpp(0, __float_as_int(y), CTRL, 0xF, 0xF, false);
    const int nz  = __builtin_amdgcn_update_dpp(0, __float_as_int(z), CTRL, 0xF, 0xF, false);
    const unsigned long long ok =
        ((unsigned long long)(unsigned int)nhi << 32) | (unsigned int)nlo;
    const bool gt = ok > key;
    key = gt ? ok : key;
    x = gt ? __int_as_float(nx) : x;
    y = gt ? __int_as_float(ny) : y;
    z = gt ? __int_as_float(nz) : z;
}

// ---------------------------------------------------------------------------
// Farthest point sampling (unchanged from round 7).
// ---------------------------------------------------------------------------
__global__ __launch_bounds__(256) void fps_kernel(
    const float* __restrict__ xyz,
    float* __restrict__ out_nxyz,   // [B,1024,3]
    float* __restrict__ out_idxf)   // [B,1024] (indices stored as float)
{
    __shared__ float sx[NPTS], sy[NPTS], sz[NPTS];
    __shared__ float4 pr0[2][4];    // {key_lo, key_hi, x, y} per wave
    __shared__ float  pr1[2][4];    // z per wave
    __shared__ int sidx[NPT];

    const int tid  = threadIdx.x;
    const int b    = blockIdx.x;
    const int lane = tid & 63;
    const int wid  = tid >> 6;

    const float* bx = xyz + (size_t)b * NPTS * 3;
    for (int p = tid; p < NPTS; p += 256) {
        sx[p] = bx[3 * p];
        sy[p] = bx[3 * p + 1];
        sz[p] = bx[3 * p + 2];
    }
    if (tid == 0) sidx[0] = 0;
    __syncthreads();

    float rx[16], ry[16], rz[16], dist[16];
#pragma unroll
    for (int j = 0; j < 16; ++j) {
        const int p = tid + j * 256;
        rx[j] = sx[p];
        ry[j] = sy[p];
        rz[j] = sz[p];
        dist[j] = 1e10f;
    }

    float lx = sx[0], ly = sy[0], lz = sz[0];

    for (int step = 1; step < NPT; ++step) {
        float bv = -1.0f;
        int   bp = 0;
#pragma unroll
        for (int j = 0; j < 16; ++j) {
            const int p = tid + j * 256;
            const float dx = __fsub_rn(rx[j], lx);
            const float dy = __fsub_rn(ry[j], ly);
            const float dz = __fsub_rn(rz[j], lz);
            const float d  = __fadd_rn(__fadd_rn(__fmul_rn(dx, dx), __fmul_rn(dy, dy)),
                                       __fmul_rn(dz, dz));
            const float nd = fminf(dist[j], d);
            dist[j] = nd;
            const bool gt = nd > bv;     // strict: first max within thread
            bv = gt ? nd : bv;
            bp = gt ? p : bp;
        }
        unsigned long long key =
            ((unsigned long long)__float_as_uint(bv) << 32) |
            (unsigned int)(~bp);

        dpp_keymax<0x111>(key);   // row_shr:1
        dpp_keymax<0x112>(key);   // row_shr:2
        dpp_keymax<0x114>(key);   // row_shr:4
        dpp_keymax<0x118>(key);   // row_shr:8
        dpp_keymax<0x142>(key);   // row_bcast15
        dpp_keymax<0x143>(key);   // row_bcast31 -> lane63 = wave max

        const int par = step & 1;
        if (lane == 63) {
            const int wix = (int)(~(unsigned int)key);
            pr0[par][wid] = make_float4(
                __int_as_float((int)(unsigned int)key),
                __int_as_float((int)(unsigned int)(key >> 32)),
                sx[wix], sy[wix]);
            pr1[par][wid] = sz[wix];
        }
        __syncthreads();

        const float4 r  = pr0[par][lane & 3];
        const float  rzz = pr1[par][lane & 3];
        unsigned long long gkey =
            ((unsigned long long)(unsigned int)__float_as_int(r.y) << 32) |
            (unsigned int)__float_as_int(r.x);
        float gx = r.z, gy = r.w, gz = rzz;
        dpp_keymax_xyz<0xB1>(gkey, gx, gy, gz);   // quad_perm xor1
        dpp_keymax_xyz<0x4E>(gkey, gx, gy, gz);   // quad_perm xor2

        lx = gx; ly = gy; lz = gz;
        if (tid == 0) sidx[step] = (int)(~(unsigned int)gkey);  // LDS only
    }
    __syncthreads();

    for (int s = tid; s < NPT; s += 256) {
        const int ix = sidx[s];
        out_idxf[b * NPT + s] = (float)ix;
        out_nxyz[(size_t)(b * NPT + s) * 3 + 0] = sx[ix];
        out_nxyz[(size_t)(b * NPT + s) * 3 + 1] = sy[ix];
        out_nxyz[(size_t)(b * NPT + s) * 3 + 2] = sz[ix];
    }
}

// ---------------------------------------------------------------------------
// One dense-layer pass, channel-quarter per lane-group.
// src: LDS activations laid out [chan][64 cols]; per c: one ds_read_b32
// (16 consecutive words per wave + 4-way same-address broadcast = conflict
// free), weight chunk via global float4 loads (wave-broadcast, L1/L2 hot).
// acc indices all compile-time static. Per output channel: c ascending fmaf
// chain == previous rounds, bit-identical.
// ---------------------------------------------------------------------------
template <int CIN, int COUT, int CH>
__device__ __forceinline__ void layer_acc(const float* __restrict__ W, int q,
                                          int col,
                                          const float* __restrict__ src,
                                          float* __restrict__ acc)
{
#pragma unroll
    for (int j = 0; j < CH; ++j) acc[j] = 0.0f;
    const float* __restrict__ Wq = W + q * CH;
#pragma unroll 4
    for (int c = 0; c < CIN; ++c) {
        const float xc = src[c * 64 + col];
        const float4* __restrict__ wr = (const float4*)(Wq + (size_t)c * COUT);
#pragma unroll
        for (int j4 = 0; j4 < CH / 4; ++j4) {
            const float4 w = wr[j4];
            acc[4 * j4 + 0] = fmaf(xc, w.x, acc[4 * j4 + 0]);
            acc[4 * j4 + 1] = fmaf(xc, w.y, acc[4 * j4 + 1]);
            acc[4 * j4 + 2] = fmaf(xc, w.z, acc[4 * j4 + 2]);
            acc[4 * j4 + 3] = fmaf(xc, w.w, acc[4 * j4 + 3]);
        }
    }
}

// ---------------------------------------------------------------------------
// Per-scale SA: channel-split layout.
// Block = 256 thr = 4 waves = 64 neighbor columns total.
//   WPQ = K/16 waves per query, NQ = 4/WPQ queries per block.
//   lane -> nb16 = lane&15 (neighbor within wave), q = lane>>4 (channel 1/4).
// Ball query: one full wave scans per query (first-K ascending, same
// semantics/float ops as before). Activations ping-pong A(96 rows)/B(64 rows)
// in LDS. Small per-lane acc (<=32) -> no AGPR/spill traffic. Pool =
// 16-lane shfl butterfly + LDS cross-wave reduce.
// ---------------------------------------------------------------------------
template <int K, int F0, int F1, int F2, int CH_OFF>
__global__ __launch_bounds__(256) void sa_kernel(
    const float* __restrict__ xyz,
    const float* __restrict__ points,
    const float* __restrict__ newxyz,
    const float* __restrict__ w0,
    const float* __restrict__ w1,
    const float* __restrict__ w2,
    float* __restrict__ out1,
    float r2)
{
    constexpr int WPQ = K / 16;      // waves per query
    constexpr int NQ  = 4 / WPQ;     // queries per block
    constexpr int CH0 = F0 / 4, CH1 = F1 / 4, CH2 = F2 / 4;

    __shared__ float A[96 * 64];     // input(19) then h1(96)
    __shared__ float Bb[64 * 64];    // h0(64)
    __shared__ int   slist[64];      // NQ * K == 64
    __shared__ int   scnt[4];
    __shared__ float pool[4][4][32]; // [wid][q][j], CH2 <= 32

    const int tid  = threadIdx.x;
    const int lane = tid & 63;
    const int wid  = tid >> 6;
    const int qlocal = wid / WPQ;
    const int nbw    = wid % WPQ;
    const int nb16   = lane & 15;
    const int q      = lane >> 4;
    const int col    = qlocal * K + nbw * 16 + nb16;
    const int qid    = blockIdx.x * NQ + qlocal;
    const int b      = qid >> 10;

    const float qx = newxyz[(size_t)qid * 3 + 0];
    const float qy = newxyz[(size_t)qid * 3 + 1];
    const float qz = newxyz[(size_t)qid * 3 + 2];
    const float* bxyz = xyz + (size_t)b * NPTS * 3;

    // ---- ball query: one wave scans for its query ----
    if (nbw == 0) {
        int cnt = 0;
        for (int c0 = 0; c0 < NPTS && cnt < K; c0 += 64) {
            const int p = c0 + lane;
            const float dx = __fsub_rn(qx, bxyz[3 * p]);
            const float dy = __fsub_rn(qy, bxyz[3 * p + 1]);
            const float dz = __fsub_rn(qz, bxyz[3 * p + 2]);
            const float d2 = __fadd_rn(__fadd_rn(__fmul_rn(dx, dx), __fmul_rn(dy, dy)),
                                       __fmul_rn(dz, dz));
            const bool hit = d2 < r2;
            const unsigned long long bal = __ballot(hit);
            const int pre = __popcll(bal & ((1ULL << lane) - 1ULL));
            const int pos = cnt + pre;
            if (hit && pos < K) slist[qlocal * K + pos] = p;
            cnt += (int)__popcll(bal);
        }
        if (lane == 0) scnt[qlocal] = (cnt < K) ? cnt : K;
    }
    __syncthreads();

    // ---- gather into A: rows 0-15 = point feats, 16-18 = rel xyz ----
    {
        const int slot = nbw * 16 + nb16;
        const int cn   = scnt[qlocal];
        const int nbr  = slist[qlocal * K + ((slot < cn) ? slot : 0)];
        if (q == 0) {
            const float4* prow = (const float4*)(points + ((size_t)b * NPTS + nbr) * 16);
            const float4 p0 = prow[0], p1 = prow[1], p2 = prow[2], p3 = prow[3];
            A[ 0 * 64 + col] = p0.x;  A[ 1 * 64 + col] = p0.y;
            A[ 2 * 64 + col] = p0.z;  A[ 3 * 64 + col] = p0.w;
            A[ 4 * 64 + col] = p1.x;  A[ 5 * 64 + col] = p1.y;
            A[ 6 * 64 + col] = p1.z;  A[ 7 * 64 + col] = p1.w;
            A[ 8 * 64 + col] = p2.x;  A[ 9 * 64 + col] = p2.y;
            A[10 * 64 + col] = p2.z;  A[11 * 64 + col] = p2.w;
            A[12 * 64 + col] = p3.x;  A[13 * 64 + col] = p3.y;
            A[14 * 64 + col] = p3.z;  A[15 * 64 + col] = p3.w;
        } else if (q == 1) {
            A[16 * 64 + col] = __fsub_rn(bxyz[3 * nbr],     qx);
            A[17 * 64 + col] = __fsub_rn(bxyz[3 * nbr + 1], qy);
            A[18 * 64 + col] = __fsub_rn(bxyz[3 * nbr + 2], qz);
        }
    }
    __syncthreads();

    // ---- layer 1: A(19 rows) -> relu -> B rows [q*CH0 .. ) ----
    {
        float acc[CH0];
        layer_acc<19, F0, CH0>(w0, q, col, A, acc);
#pragma unroll
        for (int j = 0; j < CH0; ++j)
            Bb[(q * CH0 + j) * 64 + col] = fmaxf(acc[j], 0.0f);
    }
    __syncthreads();

    // ---- layer 2: B(F0 rows) -> relu -> A rows [q*CH1 .. ) ----
    {
        float acc[CH1];
        layer_acc<F0, F1, CH1>(w1, q, col, Bb, acc);
#pragma unroll
        for (int j = 0; j < CH1; ++j)
            A[(q * CH1 + j) * 64 + col] = fmaxf(acc[j], 0.0f);
    }
    __syncthreads();

    // ---- layer 3 + relu + 16-lane butterfly pool + publish ----
    {
        float acc[CH2];
        layer_acc<F1, F2, CH2>(w2, q, col, A, acc);
#pragma unroll
        for (int j = 0; j < CH2; ++j) acc[j] = fmaxf(acc[j], 0.0f);
#pragma unroll
        for (int off = 1; off < 16; off <<= 1) {
#pragma unroll
            for (int j = 0; j < CH2; ++j)
                acc[j] = fmaxf(acc[j], __shfl_xor(acc[j], off));
        }
        if (nb16 == 0) {
#pragma unroll
            for (int j = 0; j < CH2; ++j) pool[wid][q][j] = acc[j];
        }
    }
    __syncthreads();

    // ---- cross-wave pool reduce + coalesced store ----
    if (tid < NQ * F2) {
        const int ql = tid / F2, ch = tid % F2;
        const int qg = ch / CH2, j = ch % CH2;
        float v = pool[ql * WPQ][qg][j];
#pragma unroll
        for (int w = 1; w < WPQ; ++w)
            v = fmaxf(v, pool[ql * WPQ + w][qg][j]);
        out1[(size_t)(blockIdx.x * NQ + ql) * 320 + CH_OFF + ch] = v;
    }
}

// ---------------------------------------------------------------------------
extern "C" void kernel_launch(void* const* d_in, const int* in_sizes, int n_in,
                              void* d_out, int out_size, void* d_ws, size_t ws_size,
                              hipStream_t stream)
{
    const float* xyz    = (const float*)d_in[0];
    const float* points = (const float*)d_in[1];
    const float* w00 = (const float*)d_in[2];
    const float* w01 = (const float*)d_in[3];
    const float* w02 = (const float*)d_in[4];
    const float* w10 = (const float*)d_in[5];
    const float* w11 = (const float*)d_in[6];
    const float* w12 = (const float*)d_in[7];
    const float* w20 = (const float*)d_in[8];
    const float* w21 = (const float*)d_in[9];
    const float* w22 = (const float*)d_in[10];

    float* out       = (float*)d_out;
    float* out_nxyz  = out;                       // 16*1024*3   = 49152
    float* out_feat  = out + 49152;               // 16*1024*320 = 5242880
    float* out_idxf  = out + 49152 + 5242880;     // 16*1024     = 16384

    fps_kernel<<<BATCH, 256, 0, stream>>>(xyz, out_nxyz, out_idxf);

    // scale 0: r=0.1, K=16, MLP 19->32->32->64,  CH_OFF 0   (4 queries/block)
    sa_kernel<16, 32, 32, 64, 0><<<4096, 256, 0, stream>>>(
        xyz, points, out_nxyz, w00, w01, w02, out_feat, (float)(0.1 * 0.1));
    // scale 1: r=0.2, K=32, MLP 19->64->64->128, CH_OFF 64  (2 queries/block)
    sa_kernel<32, 64, 64, 128, 64><<<8192, 256, 0, stream>>>(
        xyz, points, out_nxyz, w10, w11, w12, out_feat, (float)(0.2 * 0.2));
    // scale 2: r=0.4, K=64, MLP 19->64->96->128, CH_OFF 192 (1 query/block)
    sa_kernel<64, 64, 96, 128, 192><<<16384, 256, 0, stream>>>(
        xyz, points, out_nxyz, w20, w21, w22, out_feat, (float)(0.4 * 0.4));
}